// Round 1
// baseline (380.557 us; speedup 1.0000x reference)
//
#include <hip/hip_runtime.h>
#include <math.h>
#include <stdint.h>

#define HIDDEN 4096
#define NEXP   64
#define KC     64
#define NCHUNK (HIDDEN / KC)

// Fused MoE router: logits = X[N,H] @ W[E,H]^T + b, top-2, softmax(top2).
// Layout of d_out (all fp32): [rw N*2][sel N*2 (as float)][logits N*64][aux 1]
//
// Mapping: 512 thr = 8 waves per WG; WG owns 64 tokens; lane = token.
// Wave w owns experts [8w, 8w+8). W operand is wave-uniform -> s_load
// (scalar pipe, zero VALU/LDS cost). X staged in LDS column-blocked
// lds[g][t][4] -> per-lane ds_read_b128 is bank-balanced (8 words/bank).
__global__ __launch_bounds__(512) void router_kernel(
    const float* __restrict__ X,
    const float* __restrict__ W,
    const float* __restrict__ Bv,
    float* __restrict__ out,
    int nTok)
{
    __shared__ float smem[NEXP * 65];   // 4160 floats; staging uses first 4096

    const int tid  = threadIdx.x;
    const int lane = tid & 63;
    const int wv   = __builtin_amdgcn_readfirstlane(tid >> 6); // wave id 0..7, SGPR
    const int t0   = blockIdx.x * 64;
    const int e0   = wv * 8;

    // Staging: 1024 float4-slots per chunk; thread handles slots tid, tid+512.
    // Slot s -> token row tr = s>>4, k-group j = s&15.
    // Global read coalesced (consecutive lanes = consecutive 16B in a row).
    // LDS dest: column-blocked (j*64 + tr)*4 floats.
    const int s1 = tid, s2 = tid + 512;
    const int tr1 = s1 >> 4, j1 = s1 & 15;
    const int tr2 = s2 >> 4, j2 = s2 & 15;
    float* lw1 = &smem[(j1 * 64 + tr1) * 4];
    float* lw2 = &smem[(j2 * 64 + tr2) * 4];
    const float4* g1 = (const float4*)(X + (size_t)(t0 + tr1) * HIDDEN) + j1;
    const float4* g2 = (const float4*)(X + (size_t)(t0 + tr2) * HIDDEN) + j2;

    float acc[8];
#pragma unroll
    for (int e = 0; e < 8; ++e) acc[e] = 0.0f;

    // prologue: stage chunk 0
    {
        float4 a = g1[0];
        float4 b = g2[0];
        *(float4*)lw1 = a;
        *(float4*)lw2 = b;
    }
    __syncthreads();

    for (int c = 0; c < NCHUNK; ++c) {
        // T14: issue next chunk's global loads early; HBM latency hides
        // under this chunk's 512 FMAs.
        float4 na, nb;
        const bool more = (c + 1 < NCHUNK);
        if (more) {
            na = g1[(c + 1) * (KC / 4)];
            nb = g2[(c + 1) * (KC / 4)];
        }

        // lane's 64 X values -> VGPRs once, reused for all 8 experts
        float4 xb[16];
#pragma unroll
        for (int g = 0; g < 16; ++g)
            xb[g] = *(const float4*)&smem[(g * 64 + lane) * 4];

        const int k0 = c * KC;
#pragma unroll
        for (int e = 0; e < 8; ++e) {
            const float* wr = W + (size_t)(e0 + e) * HIDDEN + k0;  // uniform -> s_load
            float a = acc[e];
#pragma unroll
            for (int g = 0; g < 16; ++g) {
                a = fmaf(xb[g].x, wr[4 * g + 0], a);
                a = fmaf(xb[g].y, wr[4 * g + 1], a);
                a = fmaf(xb[g].z, wr[4 * g + 2], a);
                a = fmaf(xb[g].w, wr[4 * g + 3], a);
            }
            acc[e] = a;
        }
        __syncthreads();          // all waves done reading lds (drains vmcnt too)
        if (more) {
            *(float4*)lw1 = na;
            *(float4*)lw2 = nb;
        }
        __syncthreads();          // next chunk visible
    }

    // logits -> LDS transposed [e][t], stride 65 (conflict-free)
#pragma unroll
    for (int e = 0; e < 8; ++e)
        smem[(e0 + e) * 65 + lane] = acc[e] + Bv[e0 + e];
    __syncthreads();

    const size_t offSel = (size_t)nTok * 2;
    const size_t offLog = (size_t)nTok * 4;
    const size_t offAux = offLog + (size_t)nTok * NEXP;

    // top-2 + softmax: wave 0, one token per lane. Strict > keeps the
    // lowest index on ties (jax.lax.top_k semantics).
    if (tid < 64) {
        const int t = tid;
        float m1 = -INFINITY, m2 = -INFINITY;
        int i1 = 0, i2 = 0;
#pragma unroll
        for (int e = 0; e < NEXP; ++e) {
            float v = smem[e * 65 + t];
            if (v > m1)      { m2 = m1; i2 = i1; m1 = v; i1 = e; }
            else if (v > m2) { m2 = v; i2 = e; }
        }
        float ex  = expf(m2 - m1);
        float inv = 1.0f / (1.0f + ex);
        float2 rw = make_float2(inv, ex * inv);
        float2 se = make_float2((float)i1, (float)i2);  // indices as fp32
        *(float2*)(out + (size_t)(t0 + t) * 2) = rw;
        *(float2*)(out + offSel + (size_t)(t0 + t) * 2) = se;
    }

    // router_logits global write: 8 consecutive floats per thread, float4 x2
    {
        const int t  = tid >> 3;
        const int eb = (tid & 7) * 8;
        float v[8];
#pragma unroll
        for (int j = 0; j < 8; ++j)
            v[j] = smem[(eb + j) * 65 + t];
        float4* dst = (float4*)(out + offLog + (size_t)(t0 + t) * NEXP + eb);
        dst[0] = make_float4(v[0], v[1], v[2], v[3]);
        dst[1] = make_float4(v[4], v[5], v[6], v[7]);
    }

    if (blockIdx.x == 0 && tid == 0) out[offAux] = 0.0f;
}

extern "C" void kernel_launch(void* const* d_in, const int* in_sizes, int n_in,
                              void* d_out, int out_size, void* d_ws, size_t ws_size,
                              hipStream_t stream)
{
    const float* X  = (const float*)d_in[0];
    const float* W  = (const float*)d_in[1];
    const float* Bv = (const float*)d_in[2];
    float* out = (float*)d_out;
    const int nTok   = in_sizes[0] / HIDDEN;  // 16384
    const int blocks = nTok / 64;             // 256
    router_kernel<<<blocks, 512, 0, stream>>>(X, W, Bv, out, nTok);
}